// Round 1
// baseline (56.518 us; speedup 1.0000x reference)
//
#include <hip/hip_runtime.h>
#include <hip/hip_bf16.h>

// ---- problem constants ----
#define BATCH 16
#define CIN   12
#define HIMG  512
#define WIMG  512
#define OCH   768
#define KDIM  256          // 16*16 patch
#define HW    (HIMG*WIMG)  // 262144
#define NPATCH 1024        // 32*32 patches per batch
#define M_TOT (BATCH*NPATCH) // 16384

typedef __attribute__((ext_vector_type(8))) short short8;   // 8 bf16 = 4 VGPRs
typedef __attribute__((ext_vector_type(4))) float f32x4;

// ---------------------------------------------------------------------------
// Kernel 0: convert weights f32 -> bf16.  O*K = 196608 elements.
// ---------------------------------------------------------------------------
__global__ void wconv_kernel(const float* __restrict__ w, __hip_bfloat16* __restrict__ wb) {
    int idx = (blockIdx.x * blockDim.x + threadIdx.x) * 4;
    float4 v = *reinterpret_cast<const float4*>(w + idx);
    union { ushort4 u4; __hip_bfloat16 h[4]; } o;
    o.h[0] = __float2bfloat16(v.x);
    o.h[1] = __float2bfloat16(v.y);
    o.h[2] = __float2bfloat16(v.z);
    o.h[3] = __float2bfloat16(v.w);
    *reinterpret_cast<ushort4*>(wb + idx) = o.u4;
}

// ---------------------------------------------------------------------------
// Kernel 1: channel mean, f32 in -> bf16 out.  xm[b][h][w] = mean_c x.
// Each thread: 4 consecutive w positions (float4), 12 strided channel loads.
// ---------------------------------------------------------------------------
__global__ void mean_kernel(const float* __restrict__ x, __hip_bfloat16* __restrict__ xm) {
    int idx = blockIdx.x * blockDim.x + threadIdx.x;    // float4 index, 0..1048575
    int b = idx >> 16;                                  // 65536 float4 per image
    int pos = (idx & 65535) << 2;
    const float* px = x + (size_t)b * CIN * HW + pos;
    float sx = 0.f, sy = 0.f, sz = 0.f, sw = 0.f;
    #pragma unroll
    for (int c = 0; c < CIN; ++c) {
        float4 v = *reinterpret_cast<const float4*>(px + (size_t)c * HW);
        sx += v.x; sy += v.y; sz += v.z; sw += v.w;
    }
    const float inv = 1.0f / 12.0f;
    union { ushort4 u4; __hip_bfloat16 h[4]; } o;
    o.h[0] = __float2bfloat16(sx * inv);
    o.h[1] = __float2bfloat16(sy * inv);
    o.h[2] = __float2bfloat16(sz * inv);
    o.h[3] = __float2bfloat16(sw * inv);
    *reinterpret_cast<ushort4*>(xm + (size_t)idx * 4) = o.u4;
}

// ---------------------------------------------------------------------------
// Kernel 2: patch-embedding GEMM via MFMA bf16.
//   C[o][m] = sum_k Wb[o][k] * patch[m][k];  out[b][o][p] = C + bias[o]
//   patch[m][k]: m = b*1024 + i*32 + j, k = r*16 + s -> xm[b][i*16+r][j*16+s]
// Block tile: 64 o x 128 m, K-chunks of 64.  4 waves (2 o x 2 m),
// per wave 32 o x 64 m = 2x4 fragments of 16x16, mfma_f32_16x16x32_bf16.
// ---------------------------------------------------------------------------
#define BO 64
#define BM 128
#define BK 64
#define LDK 72   // +8 bf16 pad

__global__ __launch_bounds__(256) void gemm_kernel(
        const __hip_bfloat16* __restrict__ wb,   // [OCH][KDIM]
        const __hip_bfloat16* __restrict__ xm,   // [BATCH][HIMG][WIMG]
        const float* __restrict__ bias,
        float* __restrict__ out) {
    __shared__ short Al[BO][LDK];   // weights tile  (o x k)
    __shared__ short Bl[BM][LDK];   // patches tile  (m x k)

    const int mb = blockIdx.x;          // 0..127
    const int ob = blockIdx.y;          // 0..11
    const int m0 = mb * BM;
    const int o0 = ob * BO;
    const int tid  = threadIdx.x;
    const int lane = tid & 63;
    const int wv = tid >> 6;            // 0..3
    const int wo = wv >> 1;             // 0..1
    const int wm = wv & 1;              // 0..1
    const int lrow = lane & 15;
    const int lg   = lane >> 4;

    // m0 is 128-aligned and 1024 % 128 == 0 -> single batch per block
    const int b  = m0 >> 10;
    const int p0 = m0 & 1023;

    // B staging: thread -> (m-row, half): 2 threads per m-row, 4 r-rows each
    const int srow  = tid >> 1;         // 0..127
    const int shalf = tid & 1;
    const int pm = p0 + srow;
    const int pi = pm >> 5;
    const int pj = pm & 31;
    const __hip_bfloat16* xbase =
        xm + (size_t)b * HW + (size_t)(pi * 16) * WIMG + pj * 16 + shalf * 8;

    // A staging: thread -> (o-row, quarter): 4 threads per o-row, 16 k each
    const int arow = tid >> 2;          // 0..63
    const int aq   = tid & 3;
    const __hip_bfloat16* wbase = wb + (size_t)(o0 + arow) * KDIM + aq * 16;

    f32x4 acc[2][4] = {};

    for (int kc = 0; kc < 4; ++kc) {
        const int k0 = kc * BK;
        // ---- stage A (64x64 bf16) ----
        {
            const short* src = reinterpret_cast<const short*>(wbase + k0);
            *reinterpret_cast<short8*>(&Al[arow][aq * 16])     = *reinterpret_cast<const short8*>(src);
            *reinterpret_cast<short8*>(&Al[arow][aq * 16 + 8]) = *reinterpret_cast<const short8*>(src + 8);
        }
        // ---- stage B (128x64 bf16): 4 kernel-rows r of 16 s each ----
        {
            const int rc = kc * 4;
            #pragma unroll
            for (int dr = 0; dr < 4; ++dr) {
                const short* src = reinterpret_cast<const short*>(xbase + (size_t)(rc + dr) * WIMG);
                *reinterpret_cast<short8*>(&Bl[srow][dr * 16 + shalf * 8]) =
                    *reinterpret_cast<const short8*>(src);
            }
        }
        __syncthreads();
        // ---- MFMA: 2 k-substeps of 32 ----
        #pragma unroll
        for (int kk = 0; kk < 2; ++kk) {
            short8 af[2], bf[4];
            #pragma unroll
            for (int fo = 0; fo < 2; ++fo)
                af[fo] = *reinterpret_cast<const short8*>(&Al[wo * 32 + fo * 16 + lrow][kk * 32 + lg * 8]);
            #pragma unroll
            for (int fm = 0; fm < 4; ++fm)
                bf[fm] = *reinterpret_cast<const short8*>(&Bl[wm * 64 + fm * 16 + lrow][kk * 32 + lg * 8]);
            #pragma unroll
            for (int fo = 0; fo < 2; ++fo)
                #pragma unroll
                for (int fm = 0; fm < 4; ++fm)
                    acc[fo][fm] = __builtin_amdgcn_mfma_f32_16x16x32_bf16(af[fo], bf[fm], acc[fo][fm], 0, 0, 0);
        }
        __syncthreads();
    }

    // ---- epilogue: D row = o (lane>>4)*4 + reg, col = m (lane&15)  [m89] ----
    #pragma unroll
    for (int fo = 0; fo < 2; ++fo) {
        const int obase = o0 + wo * 32 + fo * 16 + lg * 4;
        #pragma unroll
        for (int r = 0; r < 4; ++r) {
            const int o = obase + r;
            const float bv = bias[o];
            float* orow = out + (size_t)b * (OCH * NPATCH) + (size_t)o * NPATCH + p0;
            #pragma unroll
            for (int fm = 0; fm < 4; ++fm)
                orow[wm * 64 + fm * 16 + lrow] = acc[fo][fm][r] + bv;
        }
    }
}

// ---------------------------------------------------------------------------
extern "C" void kernel_launch(void* const* d_in, const int* in_sizes, int n_in,
                              void* d_out, int out_size, void* d_ws, size_t ws_size,
                              hipStream_t stream) {
    const float* x    = (const float*)d_in[0];
    const float* w    = (const float*)d_in[1];
    const float* bias = (const float*)d_in[2];
    float* out = (float*)d_out;

    __hip_bfloat16* xm = (__hip_bfloat16*)d_ws;                                  // 8 MiB
    __hip_bfloat16* wbq = (__hip_bfloat16*)((char*)d_ws + (size_t)BATCH * HW * 2); // 384 KiB

    wconv_kernel<<<OCH * KDIM / (256 * 4), 256, 0, stream>>>(w, wbq);
    mean_kernel<<<BATCH * HW / 4 / 256, 256, 0, stream>>>(x, xm);
    dim3 grid(M_TOT / BM, OCH / BO);
    gemm_kernel<<<grid, 256, 0, stream>>>(wbq, xm, bias, out);
}

// Round 2
// 53.507 us; speedup vs baseline: 1.0563x; 1.0563x over previous
//
#include <hip/hip_runtime.h>
#include <hip/hip_bf16.h>

// ---- problem constants ----
#define BATCH 16
#define CIN   12
#define HIMG  512
#define WIMG  512
#define OCH   768
#define KDIM  256            // 16*16 patch
#define HW    (HIMG*WIMG)    // 262144
#define NPATCH 1024          // 32*32 patches per batch

typedef __attribute__((ext_vector_type(8))) short short8;   // 8 bf16 = 4 VGPRs
typedef __attribute__((ext_vector_type(4))) float f32x4;

// ---------------------------------------------------------------------------
// Kernel 0: convert + PACK weights f32 -> bf16 in MFMA fragment-lane order.
//   packed[u][0..7], u = (ot*8 + kk)*64 + lane
//   holds w[ot*16 + (lane&15)][kk*32 + (lane>>4)*8 + j], j=0..7
// A wave's A-fragment load becomes one fully-coalesced 1 KiB short8 load.
// ---------------------------------------------------------------------------
__global__ void wpack_kernel(const float* __restrict__ w, short8* __restrict__ wbp) {
    int u = blockIdx.x * 256 + threadIdx.x;      // 0..24575
    int lane = u & 63;
    int kk   = (u >> 6) & 7;
    int ot   = u >> 9;                           // 0..47
    int o = ot * 16 + (lane & 15);
    int k = kk * 32 + (lane >> 4) * 8;
    const float* src = w + (size_t)o * KDIM + k;
    float4 v0 = *reinterpret_cast<const float4*>(src);
    float4 v1 = *reinterpret_cast<const float4*>(src + 4);
    union { short8 s; __hip_bfloat16 h[8]; } t;
    t.h[0] = __float2bfloat16(v0.x);
    t.h[1] = __float2bfloat16(v0.y);
    t.h[2] = __float2bfloat16(v0.z);
    t.h[3] = __float2bfloat16(v0.w);
    t.h[4] = __float2bfloat16(v1.x);
    t.h[5] = __float2bfloat16(v1.y);
    t.h[6] = __float2bfloat16(v1.z);
    t.h[7] = __float2bfloat16(v1.w);
    wbp[u] = t.s;
}

// ---------------------------------------------------------------------------
// Kernel 1 (fused): channel-mean + patch-embedding GEMM.
// One block = one batch b, one patch-row stripe i (16 rows x 512 cols),
// all 768 output channels.  512 threads = 8 waves; wave wv owns o-range
// [wv*96, wv*96+96) x 32 patches = 6x2 fragments of 16x16, K=256 in 8 steps.
//   - staging: stream x (12 ch x 16 rows x 512 cols), channel-mean in regs,
//     bf16 -> LDS patch tile Bl[m=patch j][k = r*16+s]  (each x elem read
//     exactly once across the whole grid)
//   - A-fragments read directly from L2-resident packed weights
// ---------------------------------------------------------------------------
#define LDB 264   // 256 + 8 pad: stride 528 B = 132 banks == 4 mod 32

__global__ __launch_bounds__(512, 4) void fused_kernel(
        const short8* __restrict__ wbp,   // packed weights
        const float*  __restrict__ x,     // [B][C][H][W]
        const float*  __restrict__ bias,
        float* __restrict__ out) {        // [B][O][32][32]
    __shared__ short Bl[32][LDB];

    const int tid = threadIdx.x;
    const int b  = blockIdx.x >> 5;
    const int is = blockIdx.x & 31;       // stripe / patch-row index

    // ---- staging: channel mean -> LDS ----
    {
        const int col = (tid & 127) * 4;  // 0..508
        const int r0  = tid >> 7;         // 0..3
        const int j   = col >> 4;         // patch within stripe
        const int s0  = col & 15;
        const float* xb = x + (size_t)b * CIN * HW + (size_t)(is * 16) * WIMG + col;
        const float inv = 1.0f / 12.0f;
        #pragma unroll
        for (int p = 0; p < 4; ++p) {
            const int r = p * 4 + r0;
            const float* px = xb + (size_t)r * WIMG;
            float sx = 0.f, sy = 0.f, sz = 0.f, sw = 0.f;
            #pragma unroll
            for (int c = 0; c < CIN; ++c) {
                float4 v = *reinterpret_cast<const float4*>(px + (size_t)c * HW);
                sx += v.x; sy += v.y; sz += v.z; sw += v.w;
            }
            union { ushort4 u4; __hip_bfloat16 h[4]; } o;
            o.h[0] = __float2bfloat16(sx * inv);
            o.h[1] = __float2bfloat16(sy * inv);
            o.h[2] = __float2bfloat16(sz * inv);
            o.h[3] = __float2bfloat16(sw * inv);
            *reinterpret_cast<ushort4*>(&Bl[j][r * 16 + s0]) = o.u4;
        }
    }
    __syncthreads();

    // ---- MFMA compute ----
    const int lane = tid & 63;
    const int wv   = tid >> 6;           // 0..7
    const int lrow = lane & 15;
    const int lg   = lane >> 4;

    f32x4 acc[6][2] = {};
    const short8* wp = wbp + (size_t)(wv * 6) * 8 * 64 + lane;  // fo=0,kk=0 base

    #pragma unroll
    for (int kk = 0; kk < 8; ++kk) {
        short8 af[6], bf[2];
        #pragma unroll
        for (int fo = 0; fo < 6; ++fo)
            af[fo] = wp[(size_t)(fo * 8 + kk) * 64];
        #pragma unroll
        for (int fm = 0; fm < 2; ++fm)
            bf[fm] = *reinterpret_cast<const short8*>(&Bl[fm * 16 + lrow][kk * 32 + lg * 8]);
        #pragma unroll
        for (int fo = 0; fo < 6; ++fo)
            #pragma unroll
            for (int fm = 0; fm < 2; ++fm)
                acc[fo][fm] = __builtin_amdgcn_mfma_f32_16x16x32_bf16(af[fo], bf[fm], acc[fo][fm], 0, 0, 0);
    }

    // ---- epilogue: D row = o ((lane>>4)*4 + reg), col = m (lane&15) ----
    const int p0 = is * 32;
    float* ob = out + (size_t)b * OCH * NPATCH + p0;
    #pragma unroll
    for (int fo = 0; fo < 6; ++fo) {
        const int obase = wv * 96 + fo * 16 + lg * 4;
        #pragma unroll
        for (int r = 0; r < 4; ++r) {
            const int o = obase + r;
            const float bv = bias[o];
            float* orow = ob + (size_t)o * NPATCH;
            #pragma unroll
            for (int fm = 0; fm < 2; ++fm)
                orow[fm * 16 + lrow] = acc[fo][fm][r] + bv;
        }
    }
}

// ---------------------------------------------------------------------------
extern "C" void kernel_launch(void* const* d_in, const int* in_sizes, int n_in,
                              void* d_out, int out_size, void* d_ws, size_t ws_size,
                              hipStream_t stream) {
    const float* x    = (const float*)d_in[0];
    const float* w    = (const float*)d_in[1];
    const float* bias = (const float*)d_in[2];
    float* out = (float*)d_out;

    short8* wbp = (short8*)d_ws;   // 393 KiB packed bf16 weights

    wpack_kernel<<<96, 256, 0, stream>>>(w, wbp);
    fused_kernel<<<BATCH * 32, 512, 0, stream>>>(wbp, x, bias, out);
}